// Round 5
// baseline (235.047 us; speedup 1.0000x reference)
//
#include <hip/hip_runtime.h>

#define DIM 128
#define LN_EPS 1e-5f
// Column-sliced tables: 8 slices x 16 cols. bf16 tables (H, H2) and the fp32
// neighbor-sum scratch S are stored SLICE-MAJOR: [slice][node][16].
// Element offset for (node r, col c): ((c/16)*n + r)*16 + (c%16).

typedef __attribute__((ext_vector_type(8))) short bf16x8;
typedef __attribute__((ext_vector_type(4))) float f32x4;

static __device__ __forceinline__ unsigned short f2bf(float f) {
    unsigned int u = __builtin_bit_cast(unsigned int, f);
    u += 0x7fffu + ((u >> 16) & 1u);  // round-to-nearest-even
    return (unsigned short)(u >> 16);
}
static __device__ __forceinline__ float bf2f_lo(unsigned int u) {
    return __builtin_bit_cast(float, u << 16);
}
static __device__ __forceinline__ float bf2f_hi(unsigned int u) {
    return __builtin_bit_cast(float, u & 0xffff0000u);
}

// --------------------- fused: W transpose+cvt, degree count WITH rank capture
__global__ __launch_bounds__(256) void wt_count_kernel(const float* __restrict__ W1,
                                                       const float* __restrict__ W2,
                                                       unsigned short* __restrict__ Wt1,
                                                       unsigned short* __restrict__ Wt2,
                                                       const int* __restrict__ dst,
                                                       int* __restrict__ counts,
                                                       int* __restrict__ rank, int E) {
    int b = blockIdx.x;
    if (b < 128) {
        int elem = b * 256 + threadIdx.x;  // [0, 32768)
        int which = elem >> 14;
        int rest = elem & 16383;
        int c = rest >> 7;
        int k = rest & 127;
        const float* W = which ? W2 : W1;
        unsigned short* Wt = which ? Wt2 : Wt1;
        Wt[c * 128 + k] = f2bf(W[k * 128 + c]);
    } else {
        int e = (b - 128) * 256 + threadIdx.x;
        if (e < E) {
            int r = atomicAdd(&counts[dst[e]], 1);
            rank[e] = r;                       // coalesced 4B write
        }
    }
}

// ----------------- single-dispatch scan (all 49 blocks resident: ticket+flag)
__global__ __launch_bounds__(256) void scan_fused_kernel(const int* __restrict__ counts,
                                                         int* __restrict__ bsums,
                                                         int* __restrict__ bpref,
                                                         int* __restrict__ sync2,
                                                         int* __restrict__ rowptr,
                                                         float* __restrict__ dinv,
                                                         int n, int E, int nb) {
    __shared__ int ts[256];
    int tid = threadIdx.x;
    int b = blockIdx.x;
    int base = b * 1024 + tid * 4;
    int v[4];
#pragma unroll
    for (int j = 0; j < 4; ++j) {
        int i = base + j;
        v[j] = (i < n) ? counts[i] : 0;
        if (i < n) dinv[i] = rsqrtf((float)(v[j] + 1));  // +1 self-loop
    }
    int s = v[0] + v[1] + v[2] + v[3];
    ts[tid] = s;
    __syncthreads();
    for (int off = 1; off < 256; off <<= 1) {
        int t2 = (tid >= off) ? ts[tid - off] : 0;
        __syncthreads();
        ts[tid] += t2;
        __syncthreads();
    }
    int excl = ts[tid] - s;

    if (tid == 255) {
        bsums[b] = ts[255];
        __threadfence();
        int t = atomicAdd(&sync2[0], 1);
        if (t == nb - 1) {
            __threadfence();
            int acc = 0;
            for (int k = 0; k < nb; ++k) {
                int sv = bsums[k];
                bpref[k] = acc;
                acc += sv;
            }
            __threadfence();
            atomicExch(&sync2[1], 1);
        }
    }
    if (tid == 0) {
        while (atomicAdd(&sync2[1], 0) == 0) { __builtin_amdgcn_s_sleep(8); }
    }
    __syncthreads();
    __threadfence();

    int pre = bpref[b] + excl;
#pragma unroll
    for (int j = 0; j < 4; ++j) {
        int i = base + j;
        if (i < n) rowptr[i] = pre;
        pre += v[j];
    }
    if (b == 0 && tid == 0) rowptr[n] = E;
}

// ------------- merged dispatch: layer-1 MFMA GEMM (blocks [0,gG)) + CSR fill
// H output written SLICE-MAJOR for the slice-pinned gather phase.
__global__ __launch_bounds__(256) void gemm1_fill_kernel(const float* __restrict__ A,
                                                         const unsigned short* __restrict__ Bt,
                                                         const float* __restrict__ dinv,
                                                         unsigned short* __restrict__ Hs,
                                                         int n, int ntiles, int gG,
                                                         const int* __restrict__ src,
                                                         const int* __restrict__ dst,
                                                         const int* __restrict__ rowptr,
                                                         const int* __restrict__ rank,
                                                         unsigned short* __restrict__ colsrc,
                                                         int E) {
    __shared__ unsigned short Wlds[128 * 136];
    if (blockIdx.x >= gG) {
        int e = (blockIdx.x - gG) * 256 + threadIdx.x;
        if (e < E) {
            int p = rowptr[dst[e]] + rank[e];   // atomic-free fill
            colsrc[p] = (unsigned short)src[e];
        }
        return;
    }
    for (int u = threadIdx.x; u < 2048; u += 256) {
        int row = u >> 4;
        int sub = u & 15;
        *(bf16x8*)&Wlds[row * 136 + sub * 8] = *(const bf16x8*)(Bt + row * 128 + sub * 8);
    }
    __syncthreads();

    int wid = threadIdx.x >> 6;
    int lane = threadIdx.x & 63;
    int tile = blockIdx.x * 4 + wid;
    if (tile >= ntiles) tile = ntiles - 1;
    int r0 = tile * 16;
    int mrow = lane & 15;
    int kgrp = lane >> 4;

    int arow_i = r0 + mrow;
    if (arow_i > n - 1) arow_i = n - 1;
    const float* arow = A + (size_t)arow_i * DIM + kgrp * 8;

    f32x4 acc[8];
#pragma unroll
    for (int t = 0; t < 8; ++t) acc[t] = (f32x4){0.f, 0.f, 0.f, 0.f};

#pragma unroll
    for (int kc = 0; kc < 4; ++kc) {
        float4 v0 = *(const float4*)(arow + kc * 32);
        float4 v1 = *(const float4*)(arow + kc * 32 + 4);
        bf16x8 af;
        af[0] = (short)f2bf(v0.x); af[1] = (short)f2bf(v0.y);
        af[2] = (short)f2bf(v0.z); af[3] = (short)f2bf(v0.w);
        af[4] = (short)f2bf(v1.x); af[5] = (short)f2bf(v1.y);
        af[6] = (short)f2bf(v1.z); af[7] = (short)f2bf(v1.w);
#pragma unroll
        for (int t = 0; t < 8; ++t) {
            bf16x8 bfv = *(const bf16x8*)&Wlds[(t * 16 + mrow) * 136 + kc * 32 + kgrp * 8];
            acc[t] = __builtin_amdgcn_mfma_f32_16x16x32_bf16(af, bfv, acc[t], 0, 0, 0);
        }
    }

    float dv[4];
#pragma unroll
    for (int reg = 0; reg < 4; ++reg) {
        int rr = r0 + kgrp * 4 + reg;
        dv[reg] = (rr < n) ? dinv[rr] : 0.f;
    }

    __syncthreads();   // all waves done reading W from LDS

    // stage this wave's 16x128 bf16 tile (row-major) into private LDS region
    unsigned short* Wst = &Wlds[wid * 16 * 136];
#pragma unroll
    for (int t = 0; t < 8; ++t) {
#pragma unroll
        for (int reg = 0; reg < 4; ++reg) {
            Wst[(kgrp * 4 + reg) * 136 + t * 16 + mrow] = f2bf(acc[t][reg] * dv[reg]);
        }
    }

    // stream out slice-major, coalesced full lines:
    // chunk e in [0,256): slice s=e>>5, node=(e>>1)&15, half=e&1
#pragma unroll
    for (int q = 0; q < 4; ++q) {
        int e = q * 64 + lane;
        int s = e >> 5;
        int node = (e >> 1) & 15;
        int half = e & 1;
        int grow = r0 + node;
        if (grow < n) {
            *(bf16x8*)&Hs[((size_t)s * n + grow) * 16 + half * 8] =
                *(const bf16x8*)&Wst[node * 136 + s * 16 + half * 8];
        }
    }
}

// ------------- PHASE A: slice-pinned neighbor-sum gather.
// Block's slice = blockIdx.x % 8  ->  under round-robin block->XCD mapping,
// each XCD streams ONE 1.6 MB slice (L2-resident, ~12x reuse).
// 256 thr = 32 nodes/block, 8 lanes/node (2 cols each). fp32 sums -> S (nt store).
__global__ __launch_bounds__(256) void slice_gather_kernel(const int* __restrict__ rowptr,
                                                           const unsigned short* __restrict__ colsrc,
                                                           const unsigned short* __restrict__ Tb,
                                                           float* __restrict__ S,
                                                           int n) {
    int s = blockIdx.x & 7;
    int g = blockIdx.x >> 3;
    int lane = threadIdx.x & 63;
    int wid = threadIdx.x >> 6;
    int sub = lane >> 3;          // node subgroup within wave
    int sl = lane & 7;            // lane within node: cols sl*2, sl*2+1
    int r = g * 32 + wid * 8 + sub;
    int rc = (r < n) ? r : (n - 1);
    int p0 = rowptr[rc];
    int p1 = rowptr[rc + 1];
    int deg = p1 - p0;
    int m = deg;
    m = max(m, __shfl_xor(m, 1));
    m = max(m, __shfl_xor(m, 2));
    m = max(m, __shfl_xor(m, 4));
    int nch = (m + 7) >> 3;
    const unsigned short* Ts = Tb + (size_t)s * n * 16;
    int lbase = lane & ~7;
    float c0 = 0.f, c1 = 0.f;

    for (int c = 0; c < nch; ++c) {
        int cb = c * 8;
        int gi = p0 + cb + sl;
        gi = gi < p1 ? gi : p1 - 1;            // clamp: valid duplicate
        int idxv = (int)colsrc[gi];
#pragma unroll
        for (int j = 0; j < 8; ++j) {
            int sidx = __shfl(idxv, lbase + j);   // broadcast within 8-lane group
            unsigned int v = *(const unsigned int*)(Ts + (size_t)sidx * 16 + sl * 2);
            bool act = (cb + j < deg);
            c0 += act ? bf2f_lo(v) : 0.f;
            c1 += act ? bf2f_hi(v) : 0.f;
        }
    }

    if (r < n) {
        float2 st = make_float2(c0, c1);
        __builtin_nontemporal_store(
            __builtin_bit_cast(unsigned long long, st),
            (unsigned long long*)(S + ((size_t)s * n + r) * 16 + sl * 2));
    }
}

// ------------- PHASE B1: S + self -> bias+LN+ReLU -> layer-2 MFMA -> H2 (slice-major)
__global__ __launch_bounds__(128, 5) void ln_gemm_kernel(const float* __restrict__ S,
                                                         const unsigned short* __restrict__ Hs,
                                                         const float* __restrict__ dinv,
                                                         const float* __restrict__ bias,
                                                         const float* __restrict__ gamma,
                                                         const float* __restrict__ beta,
                                                         const unsigned short* __restrict__ Wt2,
                                                         unsigned short* __restrict__ H2s,
                                                         int n) {
    __shared__ unsigned short Tl[16][136];   // Y1 tile (row-major), then output tile
    int wid = threadIdx.x >> 6;
    int lane = threadIdx.x & 63;
    int r0 = blockIdx.x * 16;
    int grp = lane >> 4;   // which of 4 nodes this round
    int gl = lane & 15;    // lane within node: cols [gl*8, gl*8+8)

    float4 bb0 = ((const float4*)bias)[gl * 2];
    float4 bb1 = ((const float4*)bias)[gl * 2 + 1];
    float4 gg0 = ((const float4*)gamma)[gl * 2];
    float4 gg1 = ((const float4*)gamma)[gl * 2 + 1];
    float4 be0 = ((const float4*)beta)[gl * 2];
    float4 be1 = ((const float4*)beta)[gl * 2 + 1];

#pragma unroll
    for (int t = 0; t < 2; ++t) {
        int r = r0 + wid * 8 + t * 4 + grp;
        int rc = (r < n) ? r : (n - 1);
        float di = dinv[rc];
        size_t off = ((size_t)(gl >> 1) * n + rc) * 16 + (gl & 1) * 8;  // element offset
        uint4 su = *(const uint4*)(Hs + off);       // self-term, cols gl*8..+7
        float4 s0 = *(const float4*)(S + off);
        float4 s1 = *(const float4*)(S + off + 4);

        float a0 = bf2f_lo(su.x) + s0.x, a1 = bf2f_hi(su.x) + s0.y;
        float a2 = bf2f_lo(su.y) + s0.z, a3 = bf2f_hi(su.y) + s0.w;
        float a4 = bf2f_lo(su.z) + s1.x, a5 = bf2f_hi(su.z) + s1.y;
        float a6 = bf2f_lo(su.w) + s1.z, a7 = bf2f_hi(su.w) + s1.w;

        float v0 = a0 * di + bb0.x;
        float v1 = a1 * di + bb0.y;
        float v2 = a2 * di + bb0.z;
        float v3 = a3 * di + bb0.w;
        float v4 = a4 * di + bb1.x;
        float v5 = a5 * di + bb1.y;
        float v6 = a6 * di + bb1.z;
        float v7 = a7 * di + bb1.w;

        float s1r = v0 + v1 + v2 + v3 + v4 + v5 + v6 + v7;
        float s2r = v0 * v0 + v1 * v1 + v2 * v2 + v3 * v3 +
                    v4 * v4 + v5 * v5 + v6 * v6 + v7 * v7;
#pragma unroll
        for (int off2 = 8; off2 > 0; off2 >>= 1) {
            s1r += __shfl_xor(s1r, off2);
            s2r += __shfl_xor(s2r, off2);
        }
        float mu = s1r * (1.f / 128.f);
        float var = s2r * (1.f / 128.f) - mu * mu;
        float rstd = rsqrtf(var + LN_EPS);

        float o0 = fmaxf((v0 - mu) * rstd * gg0.x + be0.x, 0.f);
        float o1 = fmaxf((v1 - mu) * rstd * gg0.y + be0.y, 0.f);
        float o2 = fmaxf((v2 - mu) * rstd * gg0.z + be0.z, 0.f);
        float o3 = fmaxf((v3 - mu) * rstd * gg0.w + be0.w, 0.f);
        float o4 = fmaxf((v4 - mu) * rstd * gg1.x + be1.x, 0.f);
        float o5 = fmaxf((v5 - mu) * rstd * gg1.y + be1.y, 0.f);
        float o6 = fmaxf((v6 - mu) * rstd * gg1.z + be1.z, 0.f);
        float o7 = fmaxf((v7 - mu) * rstd * gg1.w + be1.w, 0.f);

        bf16x8 pk;
        pk[0] = (short)f2bf(o0); pk[1] = (short)f2bf(o1);
        pk[2] = (short)f2bf(o2); pk[3] = (short)f2bf(o3);
        pk[4] = (short)f2bf(o4); pk[5] = (short)f2bf(o5);
        pk[6] = (short)f2bf(o6); pk[7] = (short)f2bf(o7);
        *(bf16x8*)&Tl[wid * 8 + t * 4 + grp][gl * 8] = pk;
    }

    __syncthreads();

    // ---- layer-2 MFMA: this wave's 4 output col-blocks of Tl @ W2 ----
    int mrow = lane & 15;
    int kg = lane >> 4;
    f32x4 acc[4];
#pragma unroll
    for (int tt = 0; tt < 4; ++tt) acc[tt] = (f32x4){0.f, 0.f, 0.f, 0.f};

#pragma unroll
    for (int kc = 0; kc < 4; ++kc) {
        bf16x8 af = *(const bf16x8*)&Tl[mrow][kc * 32 + kg * 8];
#pragma unroll
        for (int tt = 0; tt < 4; ++tt) {
            int trow = (wid * 4 + tt) * 16 + mrow;
            bf16x8 bv = *(const bf16x8*)(Wt2 + (size_t)trow * 128 + kc * 32 + kg * 8);
            acc[tt] = __builtin_amdgcn_mfma_f32_16x16x32_bf16(af, bv, acc[tt], 0, 0, 0);
        }
    }

    float dv[4];
#pragma unroll
    for (int reg = 0; reg < 4; ++reg) {
        int rr = r0 + kg * 4 + reg;
        dv[reg] = (rr < n) ? dinv[rr] : 0.f;
    }

    __syncthreads();   // both waves done reading Tl as A-fragments

    // stage output tile (bf16, row-major) into Tl
#pragma unroll
    for (int tt = 0; tt < 4; ++tt) {
#pragma unroll
        for (int reg = 0; reg < 4; ++reg) {
            Tl[kg * 4 + reg][(wid * 4 + tt) * 16 + mrow] = f2bf(acc[tt][reg] * dv[reg]);
        }
    }
    __syncthreads();

    // stream out slice-major, coalesced
#pragma unroll
    for (int q = 0; q < 2; ++q) {
        int e = q * 128 + threadIdx.x;   // [0,256)
        int s = e >> 5;
        int node = (e >> 1) & 15;
        int half = e & 1;
        int grow = r0 + node;
        if (grow < n) {
            *(bf16x8*)&H2s[((size_t)s * n + grow) * 16 + half * 8] =
                *(const bf16x8*)&Tl[node][s * 16 + half * 8];
        }
    }
}

// ------------- PHASE B2: S + self -> bias + LN -> fp32 out (row-major)
__global__ __launch_bounds__(256, 5) void ln_out_kernel(const float* __restrict__ S,
                                                        const unsigned short* __restrict__ Hs,
                                                        const float* __restrict__ dinv,
                                                        const float* __restrict__ bias,
                                                        const float* __restrict__ gamma,
                                                        const float* __restrict__ beta,
                                                        float* __restrict__ out,
                                                        int n) {
    int wid = threadIdx.x >> 6;
    int lane = threadIdx.x & 63;
    int grp = lane >> 4;
    int gl = lane & 15;
    int r = blockIdx.x * 16 + wid * 4 + grp;
    int valid = (r < n);
    int rc = valid ? r : (n - 1);

    float di = dinv[rc];
    size_t off = ((size_t)(gl >> 1) * n + rc) * 16 + (gl & 1) * 8;
    uint4 su = *(const uint4*)(Hs + off);
    float4 s0 = *(const float4*)(S + off);
    float4 s1 = *(const float4*)(S + off + 4);

    float a0 = bf2f_lo(su.x) + s0.x, a1 = bf2f_hi(su.x) + s0.y;
    float a2 = bf2f_lo(su.y) + s0.z, a3 = bf2f_hi(su.y) + s0.w;
    float a4 = bf2f_lo(su.z) + s1.x, a5 = bf2f_hi(su.z) + s1.y;
    float a6 = bf2f_lo(su.w) + s1.z, a7 = bf2f_hi(su.w) + s1.w;

    float4 bb0 = ((const float4*)bias)[gl * 2];
    float4 bb1 = ((const float4*)bias)[gl * 2 + 1];
    float v0 = a0 * di + bb0.x;
    float v1 = a1 * di + bb0.y;
    float v2 = a2 * di + bb0.z;
    float v3 = a3 * di + bb0.w;
    float v4 = a4 * di + bb1.x;
    float v5 = a5 * di + bb1.y;
    float v6 = a6 * di + bb1.z;
    float v7 = a7 * di + bb1.w;

    float s1r = v0 + v1 + v2 + v3 + v4 + v5 + v6 + v7;
    float s2r = v0 * v0 + v1 * v1 + v2 * v2 + v3 * v3 +
                v4 * v4 + v5 * v5 + v6 * v6 + v7 * v7;
#pragma unroll
    for (int off2 = 8; off2 > 0; off2 >>= 1) {
        s1r += __shfl_xor(s1r, off2);
        s2r += __shfl_xor(s2r, off2);
    }
    float mu = s1r * (1.f / 128.f);
    float var = s2r * (1.f / 128.f) - mu * mu;
    float rstd = rsqrtf(var + LN_EPS);

    float4 gg0 = ((const float4*)gamma)[gl * 2];
    float4 gg1 = ((const float4*)gamma)[gl * 2 + 1];
    float4 be0 = ((const float4*)beta)[gl * 2];
    float4 be1 = ((const float4*)beta)[gl * 2 + 1];

    float o0 = (v0 - mu) * rstd * gg0.x + be0.x;
    float o1 = (v1 - mu) * rstd * gg0.y + be0.y;
    float o2 = (v2 - mu) * rstd * gg0.z + be0.z;
    float o3 = (v3 - mu) * rstd * gg0.w + be0.w;
    float o4 = (v4 - mu) * rstd * gg1.x + be1.x;
    float o5 = (v5 - mu) * rstd * gg1.y + be1.y;
    float o6 = (v6 - mu) * rstd * gg1.z + be1.z;
    float o7 = (v7 - mu) * rstd * gg1.w + be1.w;

    if (valid) {
        ((float4*)out)[(size_t)r * 32 + gl * 2] = make_float4(o0, o1, o2, o3);
        ((float4*)out)[(size_t)r * 32 + gl * 2 + 1] = make_float4(o4, o5, o6, o7);
    }
}

// =============================================================================
extern "C" void kernel_launch(void* const* d_in, const int* in_sizes, int n_in,
                              void* d_out, int out_size, void* d_ws, size_t ws_size,
                              hipStream_t stream) {
    const float* x   = (const float*)d_in[0];
    const int*   ei  = (const int*)d_in[1];
    const float* W1  = (const float*)d_in[2];
    const float* b1  = (const float*)d_in[3];
    const float* g1  = (const float*)d_in[4];
    const float* be1 = (const float*)d_in[5];
    const float* W2  = (const float*)d_in[6];
    const float* b2  = (const float*)d_in[7];
    const float* g2  = (const float*)d_in[8];
    const float* be2 = (const float*)d_in[9];

    int n = in_sizes[0] / DIM;   // 50000
    int E = in_sizes[1] / 2;     // 600000
    const int* src = ei;
    const int* dst = ei + E;

    char* wp = (char*)d_ws;
    auto alloc = [&](size_t bytes) {
        void* p = (void*)wp;
        wp += (bytes + 255) & ~(size_t)255;
        return p;
    };
    float*          dinv   = (float*)alloc((size_t)n * 4);
    int*            counts = (int*)alloc((size_t)(n + 64) * 4);  // +sync2 tail
    int*            sync2  = counts + n;                          // zeroed with counts
    int*            rowptr = (int*)alloc((size_t)(n + 1) * 4);
    int*            rank   = (int*)alloc((size_t)E * 4);
    int*            bsums  = (int*)alloc(256 * 4);
    int*            bpref  = (int*)alloc(256 * 4);
    unsigned short* colsrc = (unsigned short*)alloc((size_t)E * 2);
    unsigned short* Wt1    = (unsigned short*)alloc(128 * 128 * 2);
    unsigned short* Wt2    = (unsigned short*)alloc(128 * 128 * 2);
    unsigned short* Hs     = (unsigned short*)alloc((size_t)n * DIM * 2);   // slice-major
    unsigned short* H2s    = (unsigned short*)alloc((size_t)n * DIM * 2);   // slice-major
    float*          S      = (float*)alloc((size_t)n * DIM * 4);            // slice-major fp32

    hipMemsetAsync(counts, 0, (size_t)(n + 64) * 4, stream);

    // --- W transpose + degree count + rank capture (one dispatch) ---
    int gE = (E + 255) / 256;
    wt_count_kernel<<<128 + gE, 256, 0, stream>>>(W1, W2, Wt1, Wt2, dst, counts, rank, E);

    // --- CSR build: single-dispatch scan ---
    int nb1 = (n + 1023) / 1024;
    scan_fused_kernel<<<nb1, 256, 0, stream>>>(counts, bsums, bpref, sync2,
                                               rowptr, dinv, n, E, nb1);

    int ntiles = (n + 15) / 16;       // 3125
    int gG = (ntiles + 3) / 4;        // 782
    int ngrp = (n + 31) / 32;         // 1563 node-groups for phase A

    // --- layer-1 GEMM (slice-major H out) overlapped with atomic-free CSR fill ---
    gemm1_fill_kernel<<<gG + gE, 256, 0, stream>>>(x, Wt1, dinv, Hs, n, ntiles, gG,
                                                   src, dst, rowptr, rank, colsrc, E);

    // --- layer 1: slice-pinned gather -> S, then LN+ReLU+GEMM2 -> H2 ---
    slice_gather_kernel<<<ngrp * 8, 256, 0, stream>>>(rowptr, colsrc, Hs, S, n);
    ln_gemm_kernel<<<ntiles, 128, 0, stream>>>(S, Hs, dinv, b1, g1, be1, Wt2, H2s, n);

    // --- layer 2: slice-pinned gather -> S, then LN -> fp32 out ---
    slice_gather_kernel<<<ngrp * 8, 256, 0, stream>>>(rowptr, colsrc, H2s, S, n);
    ln_out_kernel<<<ntiles, 256, 0, stream>>>(S, H2s, dinv, b2, g2, be2, (float*)d_out, n);
}

// Round 7
// 203.827 us; speedup vs baseline: 1.1532x; 1.1532x over previous
//
#include <hip/hip_runtime.h>

#define DIM 128
#define LN_EPS 1e-5f

typedef __attribute__((ext_vector_type(8))) short bf16x8;
typedef __attribute__((ext_vector_type(4))) float f32x4;
typedef __attribute__((ext_vector_type(4))) unsigned int u32x4;

static __device__ __forceinline__ unsigned short f2bf(float f) {
    unsigned int u = __builtin_bit_cast(unsigned int, f);
    u += 0x7fffu + ((u >> 16) & 1u);  // round-to-nearest-even
    return (unsigned short)(u >> 16);
}
static __device__ __forceinline__ float bf2f_lo(unsigned int u) {
    return __builtin_bit_cast(float, u << 16);
}
static __device__ __forceinline__ float bf2f_hi(unsigned int u) {
    return __builtin_bit_cast(float, u & 0xffff0000u);
}
static __device__ __forceinline__ void nt_store16(void* p, bf16x8 v) {
    __builtin_nontemporal_store(__builtin_bit_cast(u32x4, v), (u32x4*)p);
}

// --------------------- fused: W transpose+cvt, degree count WITH rank capture
__global__ __launch_bounds__(256) void wt_count_kernel(const float* __restrict__ W1,
                                                       const float* __restrict__ W2,
                                                       unsigned short* __restrict__ Wt1,
                                                       unsigned short* __restrict__ Wt2,
                                                       const int* __restrict__ dst,
                                                       int* __restrict__ counts,
                                                       int* __restrict__ rank, int E) {
    int b = blockIdx.x;
    if (b < 128) {
        int elem = b * 256 + threadIdx.x;  // [0, 32768)
        int which = elem >> 14;
        int rest = elem & 16383;
        int c = rest >> 7;
        int k = rest & 127;
        const float* W = which ? W2 : W1;
        unsigned short* Wt = which ? Wt2 : Wt1;
        Wt[c * 128 + k] = f2bf(W[k * 128 + c]);
    } else {
        int e = (b - 128) * 256 + threadIdx.x;
        if (e < E) {
            int r = atomicAdd(&counts[dst[e]], 1);
            rank[e] = r;                       // coalesced 4B write
        }
    }
}

// ----------------- single-dispatch scan (all 49 blocks resident: ticket+flag)
__global__ __launch_bounds__(256) void scan_fused_kernel(const int* __restrict__ counts,
                                                         int* __restrict__ bsums,
                                                         int* __restrict__ bpref,
                                                         int* __restrict__ sync2,
                                                         int* __restrict__ rowptr,
                                                         float* __restrict__ dinv,
                                                         int n, int E, int nb) {
    __shared__ int ts[256];
    int tid = threadIdx.x;
    int b = blockIdx.x;
    int base = b * 1024 + tid * 4;
    int v[4];
#pragma unroll
    for (int j = 0; j < 4; ++j) {
        int i = base + j;
        v[j] = (i < n) ? counts[i] : 0;
        if (i < n) dinv[i] = rsqrtf((float)(v[j] + 1));  // +1 self-loop
    }
    int s = v[0] + v[1] + v[2] + v[3];
    ts[tid] = s;
    __syncthreads();
    for (int off = 1; off < 256; off <<= 1) {
        int t2 = (tid >= off) ? ts[tid - off] : 0;
        __syncthreads();
        ts[tid] += t2;
        __syncthreads();
    }
    int excl = ts[tid] - s;

    if (tid == 255) {
        bsums[b] = ts[255];
        __threadfence();
        int t = atomicAdd(&sync2[0], 1);
        if (t == nb - 1) {
            __threadfence();
            int acc = 0;
            for (int k = 0; k < nb; ++k) {
                int sv = bsums[k];
                bpref[k] = acc;
                acc += sv;
            }
            __threadfence();
            atomicExch(&sync2[1], 1);
        }
    }
    if (tid == 0) {
        while (atomicAdd(&sync2[1], 0) == 0) { __builtin_amdgcn_s_sleep(8); }
    }
    __syncthreads();
    __threadfence();

    int pre = bpref[b] + excl;
#pragma unroll
    for (int j = 0; j < 4; ++j) {
        int i = base + j;
        if (i < n) rowptr[i] = pre;
        pre += v[j];
    }
    if (b == 0 && tid == 0) rowptr[n] = E;
}

// ------------- merged dispatch: layer-1 MFMA GEMM (blocks [0,gG)) + CSR fill
// H tile staged in LDS, streamed out coalesced with NONTEMPORAL stores (no
// dirty L2 lines for the consumer gather to churn on).
__global__ __launch_bounds__(256) void gemm1_fill_kernel(const float* __restrict__ A,
                                                         const unsigned short* __restrict__ Bt,
                                                         const float* __restrict__ dinv,
                                                         unsigned short* __restrict__ H,
                                                         int n, int ntiles, int gG,
                                                         const int* __restrict__ src,
                                                         const int* __restrict__ dst,
                                                         const int* __restrict__ rowptr,
                                                         const int* __restrict__ rank,
                                                         unsigned short* __restrict__ colsrc,
                                                         int E) {
    __shared__ unsigned short Wlds[128 * 136];
    if (blockIdx.x >= gG) {
        int e = (blockIdx.x - gG) * 256 + threadIdx.x;
        if (e < E) {
            int p = rowptr[dst[e]] + rank[e];   // atomic-free fill
            colsrc[p] = (unsigned short)src[e];
        }
        return;
    }
    for (int u = threadIdx.x; u < 2048; u += 256) {
        int row = u >> 4;
        int sub = u & 15;
        *(bf16x8*)&Wlds[row * 136 + sub * 8] = *(const bf16x8*)(Bt + row * 128 + sub * 8);
    }
    __syncthreads();

    int wid = threadIdx.x >> 6;
    int lane = threadIdx.x & 63;
    int tile = blockIdx.x * 4 + wid;
    if (tile >= ntiles) tile = ntiles - 1;
    int r0 = tile * 16;
    int mrow = lane & 15;
    int kgrp = lane >> 4;

    int arow_i = r0 + mrow;
    if (arow_i > n - 1) arow_i = n - 1;
    const float* arow = A + (size_t)arow_i * DIM + kgrp * 8;

    f32x4 acc[8];
#pragma unroll
    for (int t = 0; t < 8; ++t) acc[t] = (f32x4){0.f, 0.f, 0.f, 0.f};

#pragma unroll
    for (int kc = 0; kc < 4; ++kc) {
        float4 v0 = *(const float4*)(arow + kc * 32);
        float4 v1 = *(const float4*)(arow + kc * 32 + 4);
        bf16x8 af;
        af[0] = (short)f2bf(v0.x); af[1] = (short)f2bf(v0.y);
        af[2] = (short)f2bf(v0.z); af[3] = (short)f2bf(v0.w);
        af[4] = (short)f2bf(v1.x); af[5] = (short)f2bf(v1.y);
        af[6] = (short)f2bf(v1.z); af[7] = (short)f2bf(v1.w);
#pragma unroll
        for (int t = 0; t < 8; ++t) {
            bf16x8 bfv = *(const bf16x8*)&Wlds[(t * 16 + mrow) * 136 + kc * 32 + kgrp * 8];
            acc[t] = __builtin_amdgcn_mfma_f32_16x16x32_bf16(af, bfv, acc[t], 0, 0, 0);
        }
    }

    float dv[4];
#pragma unroll
    for (int reg = 0; reg < 4; ++reg) {
        int rr = r0 + kgrp * 4 + reg;
        dv[reg] = (rr < n) ? dinv[rr] : 0.f;
    }

    __syncthreads();   // all waves done reading W from LDS

    // stage this wave's 16x128 bf16 tile into a private LDS region
    unsigned short* Wst = &Wlds[wid * 16 * 136];
#pragma unroll
    for (int t = 0; t < 8; ++t) {
#pragma unroll
        for (int reg = 0; reg < 4; ++reg) {
            Wst[(kgrp * 4 + reg) * 136 + t * 16 + mrow] = f2bf(acc[t][reg] * dv[reg]);
        }
    }
    // wave-private region: compiler's lgkmcnt ordering suffices, no barrier

    // stream out coalesced (nontemporal): 64 lanes x 16B x 4 passes = 4KB tile
#pragma unroll
    for (int q = 0; q < 4; ++q) {
        int e = q * 64 + lane;          // [0,256): 16B chunk index
        int row = e >> 4;
        int c16 = e & 15;
        int grow = r0 + row;
        if (grow < n) {
            nt_store16(&H[(size_t)grow * DIM + c16 * 8], *(const bf16x8*)&Wst[row * 136 + c16 * 8]);
        }
    }
}

// ------------- FUSED gather + LN + ReLU -> layer-2 GEMM.
// 256 threads = 4 waves per block own ONE 16-node tile; each wave gathers 4
// nodes in a SINGLE round (halves the per-wave serial latency chain vs r4).
// launch_bounds(.,3): VGPR cap ~170 so all 16 uint4 row loads stay in flight.
// Next chunk's colsrc index is prefetched before consuming the current one.
__global__ __launch_bounds__(256, 3) void gather_gemm_kernel(const int* __restrict__ rowptr,
                                                             const unsigned short* __restrict__ colsrc,
                                                             const uint4* __restrict__ H4,
                                                             const float* __restrict__ dinv,
                                                             const float* __restrict__ bias,
                                                             const float* __restrict__ gamma,
                                                             const float* __restrict__ beta,
                                                             const unsigned short* __restrict__ Wt2,
                                                             unsigned short* __restrict__ H2,
                                                             int n) {
    __shared__ unsigned short Tl[16][136];   // 4.4 KB: Y1 tile, then output tile
    int wid = threadIdx.x >> 6;   // 0..3
    int lane = threadIdx.x & 63;
    int r0 = blockIdx.x * 16;
    int grp = lane >> 4;          // which of 4 nodes in this wave
    int gl = lane & 15;           // lane within node: cols [gl*8, gl*8+8)

    int r = r0 + wid * 4 + grp;
    int rc = (r < n) ? r : (n - 1);
    float di = dinv[rc];
    uint4 su = H4[(size_t)rc * 16 + gl];   // self-loop term (pre-scaled)
    int p0 = rowptr[rc];
    int p1 = rowptr[rc + 1];
    float a0 = bf2f_lo(su.x), a1 = bf2f_hi(su.x);
    float a2 = bf2f_lo(su.y), a3 = bf2f_hi(su.y);
    float a4 = bf2f_lo(su.z), a5 = bf2f_hi(su.z);
    float a6 = bf2f_lo(su.w), a7 = bf2f_hi(su.w);

    int deg = p1 - p0;
    int m = max(deg, __shfl_xor(deg, 16));
    m = max(m, __shfl_xor(m, 32));
    int nch = (m + 15) >> 4;

    int idxv = 0;
    if (nch > 0) {
        int gi = p0 + gl;
        gi = gi < p1 ? gi : p1 - 1;
        idxv = (int)colsrc[gi];
    }
    for (int c = 0; c < nch; ++c) {
        int cb = c * 16;
        int idxn = idxv;
        if (c + 1 < nch) {                     // prefetch next chunk's indices
            int gi2 = p0 + cb + 16 + gl;
            gi2 = gi2 < p1 ? gi2 : p1 - 1;
            idxn = (int)colsrc[gi2];
        }

        uint4 h[16];
#pragma unroll
        for (int j = 0; j < 16; ++j) {
            int sS = __shfl(idxv, grp * 16 + j);   // broadcast within own group
            h[j] = H4[(size_t)sS * 16 + gl];
        }
#pragma unroll
        for (int j = 0; j < 16; ++j) {
            bool act = (cb + j < deg);             // group-uniform; cndmask
            a0 += act ? bf2f_lo(h[j].x) : 0.f;
            a1 += act ? bf2f_hi(h[j].x) : 0.f;
            a2 += act ? bf2f_lo(h[j].y) : 0.f;
            a3 += act ? bf2f_hi(h[j].y) : 0.f;
            a4 += act ? bf2f_lo(h[j].z) : 0.f;
            a5 += act ? bf2f_hi(h[j].z) : 0.f;
            a6 += act ? bf2f_lo(h[j].w) : 0.f;
            a7 += act ? bf2f_hi(h[j].w) : 0.f;
        }
        idxv = idxn;
    }

    float4 bb0 = ((const float4*)bias)[gl * 2];
    float4 bb1 = ((const float4*)bias)[gl * 2 + 1];
    float v0 = a0 * di + bb0.x;
    float v1 = a1 * di + bb0.y;
    float v2 = a2 * di + bb0.z;
    float v3 = a3 * di + bb0.w;
    float v4 = a4 * di + bb1.x;
    float v5 = a5 * di + bb1.y;
    float v6 = a6 * di + bb1.z;
    float v7 = a7 * di + bb1.w;

    float s1 = v0 + v1 + v2 + v3 + v4 + v5 + v6 + v7;
    float s2 = v0 * v0 + v1 * v1 + v2 * v2 + v3 * v3 +
               v4 * v4 + v5 * v5 + v6 * v6 + v7 * v7;
#pragma unroll
    for (int off = 8; off > 0; off >>= 1) {   // reduce within 16-lane group
        s1 += __shfl_xor(s1, off);
        s2 += __shfl_xor(s2, off);
    }
    float mu = s1 * (1.f / 128.f);
    float var = s2 * (1.f / 128.f) - mu * mu;
    float rstd = rsqrtf(var + LN_EPS);

    float4 gg0 = ((const float4*)gamma)[gl * 2];
    float4 gg1 = ((const float4*)gamma)[gl * 2 + 1];
    float4 be0 = ((const float4*)beta)[gl * 2];
    float4 be1 = ((const float4*)beta)[gl * 2 + 1];

    float o0 = fmaxf((v0 - mu) * rstd * gg0.x + be0.x, 0.f);
    float o1 = fmaxf((v1 - mu) * rstd * gg0.y + be0.y, 0.f);
    float o2 = fmaxf((v2 - mu) * rstd * gg0.z + be0.z, 0.f);
    float o3 = fmaxf((v3 - mu) * rstd * gg0.w + be0.w, 0.f);
    float o4 = fmaxf((v4 - mu) * rstd * gg1.x + be1.x, 0.f);
    float o5 = fmaxf((v5 - mu) * rstd * gg1.y + be1.y, 0.f);
    float o6 = fmaxf((v6 - mu) * rstd * gg1.z + be1.z, 0.f);
    float o7 = fmaxf((v7 - mu) * rstd * gg1.w + be1.w, 0.f);

    bf16x8 pk;
    pk[0] = (short)f2bf(o0); pk[1] = (short)f2bf(o1);
    pk[2] = (short)f2bf(o2); pk[3] = (short)f2bf(o3);
    pk[4] = (short)f2bf(o4); pk[5] = (short)f2bf(o5);
    pk[6] = (short)f2bf(o6); pk[7] = (short)f2bf(o7);
    *(bf16x8*)&Tl[wid * 4 + grp][gl * 8] = pk;

    __syncthreads();

    // ---- layer-2 MFMA: each wave computes 2 output col-blocks of Tl @ W2 ----
    int mrow = lane & 15;
    int kg = lane >> 4;
    f32x4 acc[2];
    acc[0] = (f32x4){0.f, 0.f, 0.f, 0.f};
    acc[1] = (f32x4){0.f, 0.f, 0.f, 0.f};

#pragma unroll
    for (int kc = 0; kc < 4; ++kc) {
        bf16x8 af = *(const bf16x8*)&Tl[mrow][kc * 32 + kg * 8];
#pragma unroll
        for (int tt = 0; tt < 2; ++tt) {
            int trow = (wid * 2 + tt) * 16 + mrow;
            bf16x8 bv = *(const bf16x8*)(Wt2 + (size_t)trow * 128 + kc * 32 + kg * 8);
            acc[tt] = __builtin_amdgcn_mfma_f32_16x16x32_bf16(af, bv, acc[tt], 0, 0, 0);
        }
    }

    float dv[4];
#pragma unroll
    for (int reg = 0; reg < 4; ++reg) {
        int rr = r0 + kg * 4 + reg;
        dv[reg] = (rr < n) ? dinv[rr] : 0.f;
    }

    __syncthreads();   // all waves done reading Tl as A-fragments

    // stage output tile (bf16) into Tl
#pragma unroll
    for (int tt = 0; tt < 2; ++tt) {
#pragma unroll
        for (int reg = 0; reg < 4; ++reg) {
            Tl[kg * 4 + reg][(wid * 2 + tt) * 16 + mrow] = f2bf(acc[tt][reg] * dv[reg]);
        }
    }
    __syncthreads();

    // stream out coalesced (nontemporal): 256 threads x 16B = whole 4KB tile
    {
        int e = threadIdx.x;             // [0,256)
        int row = e >> 4;
        int c16 = e & 15;
        int grow = r0 + row;
        if (grow < n) {
            nt_store16(&H2[(size_t)grow * DIM + c16 * 8], *(const bf16x8*)&Tl[row][c16 * 8]);
        }
    }
}

// ------------- final gather + bias + LN -> fp32 out (uint4 loads, 16 lanes/node)
__global__ __launch_bounds__(256, 3) void gather_out_kernel(const int* __restrict__ rowptr,
                                                            const unsigned short* __restrict__ colsrc,
                                                            const uint4* __restrict__ H4,
                                                            const float* __restrict__ dinv,
                                                            const float* __restrict__ bias,
                                                            const float* __restrict__ gamma,
                                                            const float* __restrict__ beta,
                                                            float* __restrict__ out,
                                                            int n) {
    int wid = threadIdx.x >> 6;
    int lane = threadIdx.x & 63;
    int grp = lane >> 4;
    int gl = lane & 15;
    int r = blockIdx.x * 16 + wid * 4 + grp;
    int valid = (r < n);
    int rc = valid ? r : (n - 1);

    float di = dinv[rc];
    uint4 su = H4[(size_t)rc * 16 + gl];
    int p0 = rowptr[rc];
    int p1 = rowptr[rc + 1];
    float a0 = bf2f_lo(su.x), a1 = bf2f_hi(su.x);
    float a2 = bf2f_lo(su.y), a3 = bf2f_hi(su.y);
    float a4 = bf2f_lo(su.z), a5 = bf2f_hi(su.z);
    float a6 = bf2f_lo(su.w), a7 = bf2f_hi(su.w);

    int deg = p1 - p0;
    int m = max(deg, __shfl_xor(deg, 16));
    m = max(m, __shfl_xor(m, 32));
    int nch = (m + 15) >> 4;

    int idxv = 0;
    if (nch > 0) {
        int gi = p0 + gl;
        gi = gi < p1 ? gi : p1 - 1;
        idxv = (int)colsrc[gi];
    }
    for (int c = 0; c < nch; ++c) {
        int cb = c * 16;
        int idxn = idxv;
        if (c + 1 < nch) {                     // prefetch next chunk's indices
            int gi2 = p0 + cb + 16 + gl;
            gi2 = gi2 < p1 ? gi2 : p1 - 1;
            idxn = (int)colsrc[gi2];
        }

        uint4 h[16];
#pragma unroll
        for (int j = 0; j < 16; ++j) {
            int sS = __shfl(idxv, grp * 16 + j);
            h[j] = H4[(size_t)sS * 16 + gl];
        }
#pragma unroll
        for (int j = 0; j < 16; ++j) {
            bool act = (cb + j < deg);
            a0 += act ? bf2f_lo(h[j].x) : 0.f;
            a1 += act ? bf2f_hi(h[j].x) : 0.f;
            a2 += act ? bf2f_lo(h[j].y) : 0.f;
            a3 += act ? bf2f_hi(h[j].y) : 0.f;
            a4 += act ? bf2f_lo(h[j].z) : 0.f;
            a5 += act ? bf2f_hi(h[j].z) : 0.f;
            a6 += act ? bf2f_lo(h[j].w) : 0.f;
            a7 += act ? bf2f_hi(h[j].w) : 0.f;
        }
        idxv = idxn;
    }

    float4 bb0 = ((const float4*)bias)[gl * 2];
    float4 bb1 = ((const float4*)bias)[gl * 2 + 1];
    float v0 = a0 * di + bb0.x;
    float v1 = a1 * di + bb0.y;
    float v2 = a2 * di + bb0.z;
    float v3 = a3 * di + bb0.w;
    float v4 = a4 * di + bb1.x;
    float v5 = a5 * di + bb1.y;
    float v6 = a6 * di + bb1.z;
    float v7 = a7 * di + bb1.w;

    float s1 = v0 + v1 + v2 + v3 + v4 + v5 + v6 + v7;
    float s2 = v0 * v0 + v1 * v1 + v2 * v2 + v3 * v3 +
               v4 * v4 + v5 * v5 + v6 * v6 + v7 * v7;
#pragma unroll
    for (int off = 8; off > 0; off >>= 1) {
        s1 += __shfl_xor(s1, off);
        s2 += __shfl_xor(s2, off);
    }
    float mu = s1 * (1.f / 128.f);
    float var = s2 * (1.f / 128.f) - mu * mu;
    float rstd = rsqrtf(var + LN_EPS);

    float4 gg0 = ((const float4*)gamma)[gl * 2];
    float4 gg1 = ((const float4*)gamma)[gl * 2 + 1];
    float4 be0 = ((const float4*)beta)[gl * 2];
    float4 be1 = ((const float4*)beta)[gl * 2 + 1];

    float o0 = (v0 - mu) * rstd * gg0.x + be0.x;
    float o1 = (v1 - mu) * rstd * gg0.y + be0.y;
    float o2 = (v2 - mu) * rstd * gg0.z + be0.z;
    float o3 = (v3 - mu) * rstd * gg0.w + be0.w;
    float o4 = (v4 - mu) * rstd * gg1.x + be1.x;
    float o5 = (v5 - mu) * rstd * gg1.y + be1.y;
    float o6 = (v6 - mu) * rstd * gg1.z + be1.z;
    float o7 = (v7 - mu) * rstd * gg1.w + be1.w;

    if (valid) {
        ((float4*)out)[(size_t)r * 32 + gl * 2] = make_float4(o0, o1, o2, o3);
        ((float4*)out)[(size_t)r * 32 + gl * 2 + 1] = make_float4(o4, o5, o6, o7);
    }
}

// =============================================================================
extern "C" void kernel_launch(void* const* d_in, const int* in_sizes, int n_in,
                              void* d_out, int out_size, void* d_ws, size_t ws_size,
                              hipStream_t stream) {
    const float* x   = (const float*)d_in[0];
    const int*   ei  = (const int*)d_in[1];
    const float* W1  = (const float*)d_in[2];
    const float* b1  = (const float*)d_in[3];
    const float* g1  = (const float*)d_in[4];
    const float* be1 = (const float*)d_in[5];
    const float* W2  = (const float*)d_in[6];
    const float* b2  = (const float*)d_in[7];
    const float* g2  = (const float*)d_in[8];
    const float* be2 = (const float*)d_in[9];

    int n = in_sizes[0] / DIM;   // 50000
    int E = in_sizes[1] / 2;     // 600000
    const int* src = ei;
    const int* dst = ei + E;

    char* wp = (char*)d_ws;
    auto alloc = [&](size_t bytes) {
        void* p = (void*)wp;
        wp += (bytes + 255) & ~(size_t)255;
        return p;
    };
    float*          dinv   = (float*)alloc((size_t)n * 4);
    int*            counts = (int*)alloc((size_t)(n + 64) * 4);  // +sync2 tail
    int*            sync2  = counts + n;                          // zeroed with counts
    int*            rowptr = (int*)alloc((size_t)(n + 1) * 4);
    int*            rank   = (int*)alloc((size_t)E * 4);
    int*            bsums  = (int*)alloc(256 * 4);
    int*            bpref  = (int*)alloc(256 * 4);
    unsigned short* colsrc = (unsigned short*)alloc((size_t)E * 2);
    unsigned short* Wt1    = (unsigned short*)alloc(128 * 128 * 2);
    unsigned short* Wt2    = (unsigned short*)alloc(128 * 128 * 2);
    unsigned short* H      = (unsigned short*)alloc((size_t)n * DIM * 2);
    unsigned short* H2     = (unsigned short*)alloc((size_t)n * DIM * 2);

    hipMemsetAsync(counts, 0, (size_t)(n + 64) * 4, stream);

    // --- W transpose + degree count + rank capture (one dispatch) ---
    int gE = (E + 255) / 256;
    wt_count_kernel<<<128 + gE, 256, 0, stream>>>(W1, W2, Wt1, Wt2, dst, counts, rank, E);

    // --- CSR build: single-dispatch scan ---
    int nb1 = (n + 1023) / 1024;
    scan_fused_kernel<<<nb1, 256, 0, stream>>>(counts, bsums, bpref, sync2,
                                               rowptr, dinv, n, E, nb1);

    int ntiles = (n + 15) / 16;       // 3125
    int gG = (ntiles + 3) / 4;        // 782

    // --- layer-1 GEMM overlapped with atomic-free CSR fill ---
    gemm1_fill_kernel<<<gG + gE, 256, 0, stream>>>(x, Wt1, dinv, H, n, ntiles, gG,
                                                   src, dst, rowptr, rank, colsrc, E);

    // --- gather+LN+ReLU fused with layer-2 GEMM (4-wave, single-round gather) ---
    gather_gemm_kernel<<<ntiles, 256, 0, stream>>>(rowptr, colsrc, (const uint4*)H, dinv,
                                                   b1, g1, be1, Wt2, H2, n);

    // --- final gather + LN -> fp32 out ---
    gather_out_kernel<<<ntiles, 256, 0, stream>>>(rowptr, colsrc, (const uint4*)H2, dinv,
                                                  b2, g2, be2, (float*)d_out, n);
}